// Round 1
// baseline (1742.611 us; speedup 1.0000x reference)
//
#include <hip/hip_runtime.h>
#include <math.h>

// Problem constants
// B=16, C=128, X=128, Y=128, heads=8, dh=32, inner=256, n=16384
// ws layout (float offsets)
#define OFF_MU    0u          // [262144]  mu per (b,c,x)
#define OFF_RSTD  262144u     // [262144]
#define OFF_WT    524288u     // wT[c=128][o=768]
#define OFF_WOT   622592u     // woT[cp=256][o=128]
#define OFF_CTXP  655360u     // [bh=128][x=128][1024]  fp32 block partials of U[d][e]
#define OFF_SEXP  17432576u   // [bh=128][x=128][32]    fp32 block partials of sumexp[d]
#define OFF_CTXS  17956864u   // [bh=128][1024]         scaled context
// total floats = 18087936 (~69 MiB)

// ---------------- K_A: transpose weights ----------------
__global__ void prep_kernel(const float* __restrict__ wqkv,
                            const float* __restrict__ wout,
                            float* __restrict__ ws) {
  int idx = blockIdx.x * 256 + threadIdx.x;   // grid covers exactly 98304+32768
  if (idx < 768 * 128) {
    int o = idx >> 7, c = idx & 127;
    ws[OFF_WT + (unsigned)c * 768u + (unsigned)o] = wqkv[idx];
  } else {
    int j = idx - 768 * 128;                  // < 32768
    int o = j >> 8, cp = j & 255;
    ws[OFF_WOT + (unsigned)cp * 128u + (unsigned)o] = wout[j];
  }
}

// ---------------- K_B: LN0 stats (per (b,c,x) row over y) ----------------
__global__ void ln0_stats_kernel(const float* __restrict__ fmap,
                                 float* __restrict__ ws) {
  const int wid = threadIdx.x >> 6, lane = threadIdx.x & 63;
  const int row = blockIdx.x * 4 + wid;       // < 262144
  const float* p = fmap + (size_t)row * 128;
  float a0 = p[lane], a1 = p[lane + 64];
  double s = (double)a0 + (double)a1;
  double q = (double)a0 * a0 + (double)a1 * a1;
  #pragma unroll
  for (int off = 32; off; off >>= 1) {
    s += __shfl_xor(s, off);
    q += __shfl_xor(q, off);
  }
  if (lane == 0) {
    double mu = s * (1.0 / 128.0);
    double var = q * (1.0 / 128.0) - mu * mu;
    ws[OFF_MU + row] = (float)mu;
    ws[OFF_RSTD + row] = (float)(1.0 / sqrt(var + 1e-5));
  }
}

// ---------------- K_C: K/V + context partials, one block per (b,h,x) ----------------
// LDS: phase1: fmch[32][128]@0, wch[32][64]@4096 ; phase2: pbuf[128][33]@0, vbuf[128][33]@4224
// stats muS/rsS/g0S/b0S @8448
__launch_bounds__(256)
__global__ void kv_ctx_kernel(const float* __restrict__ fmap,
                              const float* __restrict__ g0,
                              const float* __restrict__ b0,
                              float* __restrict__ ws) {
  __shared__ float sm[8960];
  const int x = blockIdx.x;
  const int bh = blockIdx.y;
  const int b = bh >> 3, h = bh & 7;
  const int t = threadIdx.x;

  float* muS = sm + 8448;
  float* rsS = muS + 128;
  float* g0S = rsS + 128;
  float* b0S = g0S + 128;
  if (t < 128) {
    muS[t] = ws[OFF_MU + ((unsigned)(b * 128 + t)) * 128u + x];
    rsS[t] = ws[OFF_RSTD + ((unsigned)(b * 128 + t)) * 128u + x];
    g0S[t] = g0[t];
    b0S[t] = b0[t];
  }
  __syncthreads();

  // phase 1: rows j: j<32 -> k (o=256+h*32+j), j>=32 -> v (o=512+h*32+j-32)
  const int og = t >> 4, yg = t & 15;
  const int j0 = og * 4, y0 = yg * 8;
  float acc[4][8];
  #pragma unroll
  for (int jj = 0; jj < 4; ++jj)
    #pragma unroll
    for (int yy = 0; yy < 8; ++yy) acc[jj][yy] = 0.0f;

  const float* wT = ws + OFF_WT;
  const float* fb = fmap + (((size_t)b * 128) * 128 + x) * 128;

  for (int cc = 0; cc < 4; ++cc) {
    __syncthreads();
    #pragma unroll
    for (int i = 0; i < 16; ++i) {              // stage fm chunk (LN0 applied)
      int idx = i * 256 + t;
      int c = idx >> 7, y = idx & 127;
      int cg = cc * 32 + c;
      float raw = fb[(size_t)cg * 16384 + y];
      sm[c * 128 + y] = (raw - muS[cg]) * rsS[cg] * g0S[y] + b0S[y];
    }
    #pragma unroll
    for (int i = 0; i < 8; ++i) {               // stage weight chunk
      int idx = i * 256 + t;
      int c = idx >> 6, j = idx & 63;
      int o = (j < 32) ? (256 + h * 32 + j) : (512 + h * 32 + (j - 32));
      sm[4096 + c * 64 + j] = wT[(size_t)(cc * 32 + c) * 768 + o];
    }
    __syncthreads();
    #pragma unroll 4
    for (int c = 0; c < 32; ++c) {
      const float4 w4 = *(const float4*)&sm[4096 + c * 64 + j0];
      const float4 f0 = *(const float4*)&sm[c * 128 + y0];
      const float4 f1 = *(const float4*)&sm[c * 128 + y0 + 4];
      const float wv[4] = {w4.x, w4.y, w4.z, w4.w};
      const float fv[8] = {f0.x, f0.y, f0.z, f0.w, f1.x, f1.y, f1.z, f1.w};
      #pragma unroll
      for (int jj = 0; jj < 4; ++jj)
        #pragma unroll
        for (int yy = 0; yy < 8; ++yy)
          acc[jj][yy] = fmaf(wv[jj], fv[yy], acc[jj][yy]);
    }
  }
  __syncthreads();   // fmch/wch dead; pbuf/vbuf alias them

  float* pbuf = sm;          // [128][33] exp(kraw)
  float* vbuf = sm + 4224;   // [128][33] vraw -> vnorm
  #pragma unroll
  for (int jj = 0; jj < 4; ++jj)
    #pragma unroll
    for (int yy = 0; yy < 8; ++yy) {
      int y = y0 + yy;
      if (og < 8) pbuf[y * 33 + (j0 + jj)] = expf(acc[jj][yy]);
      else        vbuf[y * 33 + (j0 - 32 + jj)] = acc[jj][yy];
    }
  __syncthreads();
  if (t < 128) {                               // l2-normalize v rows
    double ss = 0.0;
    #pragma unroll
    for (int e = 0; e < 32; ++e) { float v = vbuf[t * 33 + e]; ss += (double)v * v; }
    float rn = (float)(1.0 / fmax(sqrt(ss), 1e-12));
    #pragma unroll
    for (int e = 0; e < 32; ++e) vbuf[t * 33 + e] *= rn;
  }
  __syncthreads();

  // phase 2: U[d][e] partials (fp64) ; thread -> d = t>>3, e0 = (t&7)*4
  {
    const int d = t >> 3, e0 = (t & 7) * 4;
    double a0 = 0, a1 = 0, a2 = 0, a3 = 0, se = 0;
    for (int y = 0; y < 128; ++y) {
      const float pv = pbuf[y * 33 + d];
      const float v0 = vbuf[y * 33 + e0 + 0];
      const float v1 = vbuf[y * 33 + e0 + 1];
      const float v2 = vbuf[y * 33 + e0 + 2];
      const float v3 = vbuf[y * 33 + e0 + 3];
      a0 += (double)pv * v0;
      a1 += (double)pv * v1;
      a2 += (double)pv * v2;
      a3 += (double)pv * v3;
      se += (double)pv;
    }
    float* cp = ws + OFF_CTXP + ((size_t)bh * 128 + x) * 1024 + d * 32 + e0;
    cp[0] = (float)a0; cp[1] = (float)a1; cp[2] = (float)a2; cp[3] = (float)a3;
    if ((t & 7) == 0)
      ws[OFF_SEXP + ((size_t)bh * 128 + x) * 32 + d] = (float)se;
  }
}

// ---------------- K_D: reduce partials over x, scale context ----------------
__global__ void ctx_reduce_kernel(float* __restrict__ ws) {
  __shared__ double sume[32];
  const int bh = blockIdx.x;
  const int t = threadIdx.x;
  if (t < 32) {
    double a = 0;
    for (int x = 0; x < 128; ++x)
      a += (double)ws[OFF_SEXP + ((size_t)bh * 128 + x) * 32 + t];
    sume[t] = a;
  }
  __syncthreads();
  const double scale_base = (1.0 / 16384.0) * 0.17677669529663688;  // inv^2 * dh^-0.5
  #pragma unroll
  for (int i = 0; i < 4; ++i) {
    int de = t + 256 * i;
    double a = 0;
    for (int x = 0; x < 128; ++x)
      a += (double)ws[OFF_CTXP + ((size_t)bh * 128 + x) * 1024 + de];
    int d = de >> 5;
    ws[OFF_CTXS + (size_t)bh * 1024 + de] = (float)(a * scale_base / sume[d]);
  }
}

// ---------------- K_E: Q -> softmax -> q@ctx -> gelu -> out-conv -> LN1, per (b,x) ----------------
// LDS floats: fmch[32][128]@0 (alias red_s@0, red_q@2048), wch[32][64]@4096,
//             gq[64][132]@6144, stats@14592, lnmu/lnrs@15104
__launch_bounds__(256)
__global__ void final_kernel(const float* __restrict__ fmap,
                             const float* __restrict__ g0,
                             const float* __restrict__ b0,
                             const float* __restrict__ g1,
                             const float* __restrict__ b1,
                             const float* __restrict__ ws,
                             float* __restrict__ out) {
  __shared__ float sm[15360];
  const int x = blockIdx.x, b = blockIdx.y, t = threadIdx.x;

  float* gq  = sm + 6144;
  float* muS = sm + 14592;
  float* rsS = muS + 128;
  float* g0S = rsS + 128;
  float* b0S = g0S + 128;
  float* lnmu = sm + 15104;
  float* lnrs = lnmu + 128;
  if (t < 128) {
    muS[t] = ws[OFF_MU + ((unsigned)(b * 128 + t)) * 128u + x];
    rsS[t] = ws[OFF_RSTD + ((unsigned)(b * 128 + t)) * 128u + x];
    g0S[t] = g0[t];
    b0S[t] = b0[t];
  }

  const int og = t >> 4, yg = t & 15;
  const int oo0 = og * 8, y0 = yg * 8, r0 = og * 4;
  float o2[8][8];
  #pragma unroll
  for (int i = 0; i < 8; ++i)
    #pragma unroll
    for (int jv = 0; jv < 8; ++jv) o2[i][jv] = 0.0f;

  const float* wT  = ws + OFF_WT;
  const float* woT = ws + OFF_WOT;
  const float* fb  = fmap + (((size_t)b * 128) * 128 + x) * 128;
  __syncthreads();

  for (int hp = 0; hp < 4; ++hp) {
    // --- Q mini-matmul for head pair hp (rows o = hp*64 + [0,64)) ---
    float qa[4][8];
    #pragma unroll
    for (int jj = 0; jj < 4; ++jj)
      #pragma unroll
      for (int yy = 0; yy < 8; ++yy) qa[jj][yy] = 0.0f;

    for (int cc = 0; cc < 4; ++cc) {
      __syncthreads();
      #pragma unroll
      for (int i = 0; i < 16; ++i) {
        int idx = i * 256 + t;
        int c = idx >> 7, y = idx & 127;
        int cg = cc * 32 + c;
        float raw = fb[(size_t)cg * 16384 + y];
        sm[c * 128 + y] = (raw - muS[cg]) * rsS[cg] * g0S[y] + b0S[y];
      }
      #pragma unroll
      for (int i = 0; i < 8; ++i) {
        int idx = i * 256 + t;
        int c = idx >> 6, j = idx & 63;
        sm[4096 + c * 64 + j] = wT[(size_t)(cc * 32 + c) * 768 + hp * 64 + j];
      }
      __syncthreads();
      #pragma unroll 4
      for (int c = 0; c < 32; ++c) {
        const float4 w4 = *(const float4*)&sm[4096 + c * 64 + r0];
        const float4 f0 = *(const float4*)&sm[c * 128 + y0];
        const float4 f1 = *(const float4*)&sm[c * 128 + y0 + 4];
        const float wv[4] = {w4.x, w4.y, w4.z, w4.w};
        const float fv[8] = {f0.x, f0.y, f0.z, f0.w, f1.x, f1.y, f1.z, f1.w};
        #pragma unroll
        for (int jj = 0; jj < 4; ++jj)
          #pragma unroll
          for (int yy = 0; yy < 8; ++yy)
            qa[jj][yy] = fmaf(wv[jj], fv[yy], qa[jj][yy]);
      }
    }
    __syncthreads();   // everyone past gq reads of previous iteration
    #pragma unroll
    for (int jj = 0; jj < 4; ++jj)
      #pragma unroll
      for (int yy = 0; yy < 8; ++yy)
        gq[(r0 + jj) * 132 + y0 + yy] = qa[jj][yy];
    __syncthreads();

    // --- softmax over d, q@ctx, gelu; thread -> (y = t&127, head-half hh = t>>7) ---
    {
      const int yq = t & 127, hh = t >> 7;
      float m = -3.4e38f;
      #pragma unroll
      for (int dd = 0; dd < 32; ++dd)
        m = fmaxf(m, gq[(hh * 32 + dd) * 132 + yq]);
      const float* ctx = ws + OFF_CTXS + (size_t)(b * 8 + hp * 2 + hh) * 1024;
      float ge[32];
      #pragma unroll
      for (int e = 0; e < 32; ++e) ge[e] = 0.0f;
      float ssum = 0.0f;
      #pragma unroll 8
      for (int dd = 0; dd < 32; ++dd) {
        float p = expf(gq[(hh * 32 + dd) * 132 + yq] - m);
        ssum += p;
        #pragma unroll
        for (int e = 0; e < 32; ++e)
          ge[e] = fmaf(p, ctx[dd * 32 + e], ge[e]);
      }
      const float rinv = 1.0f / ssum;
      #pragma unroll
      for (int e = 0; e < 32; ++e) {
        float v = ge[e] * rinv;
        float gl = 0.5f * v * (1.0f + erff(v * 0.70710678118654752f));
        gq[(hh * 32 + e) * 132 + yq] = gl;   // same column this thread read: safe
      }
    }
    __syncthreads();

    // --- out-conv accumulate: o2[o][y] += woT[cp][o] * gel[cp][y] ---
    #pragma unroll 2
    for (int e = 0; e < 64; ++e) {
      int cpg = hp * 64 + e;
      const float4 wA = *(const float4*)&woT[(size_t)cpg * 128 + oo0];
      const float4 wB = *(const float4*)&woT[(size_t)cpg * 128 + oo0 + 4];
      const float4 gA = *(const float4*)&gq[e * 132 + y0];
      const float4 gB = *(const float4*)&gq[e * 132 + y0 + 4];
      const float wv[8] = {wA.x, wA.y, wA.z, wA.w, wB.x, wB.y, wB.z, wB.w};
      const float gv[8] = {gA.x, gA.y, gA.z, gA.w, gB.x, gB.y, gB.z, gB.w};
      #pragma unroll
      for (int oo = 0; oo < 8; ++oo)
        #pragma unroll
        for (int yy = 0; yy < 8; ++yy)
          o2[oo][yy] = fmaf(wv[oo], gv[yy], o2[oo][yy]);
    }
  }
  __syncthreads();

  // --- LN1 over y per o-row ---
  float* red_s = sm;           // alias fmch region (dead)
  float* red_q = sm + 2048;
  #pragma unroll
  for (int oo = 0; oo < 8; ++oo) {
    float s = 0.0f, q = 0.0f;
    #pragma unroll
    for (int yy = 0; yy < 8; ++yy) { float v = o2[oo][yy]; s += v; q += v * v; }
    red_s[(oo0 + oo) * 16 + yg] = s;
    red_q[(oo0 + oo) * 16 + yg] = q;
  }
  __syncthreads();
  if (t < 128) {
    double s = 0, q = 0;
    #pragma unroll
    for (int i = 0; i < 16; ++i) { s += red_s[t * 16 + i]; q += red_q[t * 16 + i]; }
    double mu = s * (1.0 / 128.0);
    double var = q * (1.0 / 128.0) - mu * mu;
    lnmu[t] = (float)mu;
    lnrs[t] = (float)(1.0 / sqrt(var + 1e-5));
  }
  __syncthreads();
  #pragma unroll
  for (int oo = 0; oo < 8; ++oo) {
    int o = oo0 + oo;
    float muv = lnmu[o], rv = lnrs[o];
    float* po = out + (((size_t)b * 128 + o) * 128 + x) * 128;
    #pragma unroll
    for (int yy = 0; yy < 8; ++yy) {
      int y = y0 + yy;
      po[y] = (o2[oo][yy] - muv) * rv * g1[y] + b1[y];
    }
  }
}

extern "C" void kernel_launch(void* const* d_in, const int* in_sizes, int n_in,
                              void* d_out, int out_size, void* d_ws, size_t ws_size,
                              hipStream_t stream) {
  const float* fmap = (const float*)d_in[0];
  const float* g0   = (const float*)d_in[1];
  const float* b0   = (const float*)d_in[2];
  const float* wqkv = (const float*)d_in[3];
  const float* wout = (const float*)d_in[4];
  const float* g1   = (const float*)d_in[5];
  const float* b1   = (const float*)d_in[6];
  float* ws  = (float*)d_ws;
  float* out = (float*)d_out;

  prep_kernel<<<512, 256, 0, stream>>>(wqkv, wout, ws);
  ln0_stats_kernel<<<65536, 256, 0, stream>>>(fmap, ws);
  kv_ctx_kernel<<<dim3(128, 128), 256, 0, stream>>>(fmap, g0, b0, ws);
  ctx_reduce_kernel<<<128, 256, 0, stream>>>(ws);
  final_kernel<<<dim3(128, 16), 256, 0, stream>>>(fmap, g0, b0, g1, b1, ws, out);
}

// Round 2
// 1357.696 us; speedup vs baseline: 1.2835x; 1.2835x over previous
//
#include <hip/hip_runtime.h>
#include <math.h>

// B=16, C=128, X=128, Y=128, heads=8, dh=32, inner=256
// ws layout (float offsets), total 2949120 floats = 11.8 MB
#define OFF_MU    0u          // [262144] per (b,c,x)
#define OFF_RSTD  262144u
#define OFF_WT    524288u     // wT[c=128][o=768]
#define OFF_WOT   622592u     // woT[cp=256][o=128]
#define OFF_CTXA  655360u     // [bh=128][xg=16][1056] atomic partials (U 1024 + sexp 32)
#define OFF_CTXS  2818048u    // [bh=128][1024] scaled context

// ---------------- prep: weight transposes ----------------
__global__ void prep_kernel(const float* __restrict__ wqkv,
                            const float* __restrict__ wout,
                            float* __restrict__ ws) {
  int idx = blockIdx.x * 256 + threadIdx.x;   // 512 blocks covers 98304+32768
  if (idx < 98304) {
    int o = idx >> 7, c = idx & 127;
    ws[OFF_WT + (unsigned)c * 768u + (unsigned)o] = wqkv[idx];
  } else {
    int j = idx - 98304;
    int o = j >> 8, cp = j & 255;
    ws[OFF_WOT + (unsigned)cp * 128u + (unsigned)o] = wout[j];
  }
}

// ---------------- LN0 stats per (b,c,x) row over y ----------------
__global__ void ln0_stats_kernel(const float* __restrict__ fmap,
                                 float* __restrict__ ws) {
  const int wid = threadIdx.x >> 6, lane = threadIdx.x & 63;
  const int row = blockIdx.x * 4 + wid;       // < 262144
  const float* p = fmap + (size_t)row * 128;
  float a0 = p[lane], a1 = p[lane + 64];
  double s = (double)a0 + (double)a1;
  double q = (double)a0 * a0 + (double)a1 * a1;
  #pragma unroll
  for (int off = 32; off; off >>= 1) {
    s += __shfl_xor(s, off);
    q += __shfl_xor(q, off);
  }
  if (lane == 0) {
    double mu = s * (1.0 / 128.0);
    double var = q * (1.0 / 128.0) - mu * mu;
    ws[OFF_MU + row] = (float)mu;
    ws[OFF_RSTD + row] = (float)(1.0 / sqrt(var + 1e-5));
  }
}

// ---------------- K1: all-heads K/V + context partials, one block per (b,x) ----------------
// LDS floats: fm[32][128]@0, w[32][128]@4096 (both aliased by red[512][16] in U-reduce),
// pbuf[64][36]@8192, vbuf[64][36]@10496, vss[4][64]@12800, sered[8][8][4]@13056,
// muS@13312, rsS@13440, g0S@13568, b0S@13696, rnS[64]@13824 -> 13888 floats = 55.5 KB
__launch_bounds__(512, 4)
__global__ void kv_ctx_kernel(const float* __restrict__ fmap,
                              const float* __restrict__ g0,
                              const float* __restrict__ b0,
                              float* __restrict__ ws) {
  __shared__ float sm[13888];
  const int x = blockIdx.x, b = blockIdx.y, t = threadIdx.x;
  const int wave = t >> 6, lane = t & 63;
  // tile mapping: per-wave yg spans 16 consecutive values -> LDS reads span 64
  // consecutive floats -> 2-way bank aliasing (free, m136)
  const int og = (wave >> 1) * 4 + (lane >> 4);   // 0..15 (4 consecutive per wave)
  const int yg = (wave & 1) * 16 + (lane & 15);   // 0..31
  float* fmS = sm;
  float* wS  = sm + 4096;
  float* pb  = sm + 8192;
  float* vb  = sm + 10496;
  float* vss = sm + 12800;
  float* ser = sm + 13056;
  float* muS = sm + 13312;
  float* rsS = sm + 13440;
  float* g0S = sm + 13568;
  float* b0S = sm + 13696;
  float* rnS = sm + 13824;

  if (t < 128) {
    muS[t] = ws[OFF_MU + (unsigned)((b * 128 + t) * 128 + x)];
    rsS[t] = ws[OFF_RSTD + (unsigned)((b * 128 + t) * 128 + x)];
  } else if (t < 256) g0S[t - 128] = g0[t - 128];
  else if (t < 384) b0S[t - 256] = b0[t - 256];

  const int xg = x >> 3;
  const int dt = lane >> 3, et = lane & 7;

  for (int blk = 0; blk < 4; ++blk) {           // blk covers heads 2*blk, 2*blk+1
    float acc[8][4];
    #pragma unroll
    for (int i = 0; i < 8; ++i)
      #pragma unroll
      for (int j = 0; j < 4; ++j) acc[i][j] = 0.0f;

    for (int cc = 0; cc < 4; ++cc) {
      __syncthreads();                          // fm/w (or red) region free
      #pragma unroll
      for (int it = 0; it < 2; ++it) {          // stage fm chunk, LN0 applied
        int idx4 = it * 512 + t;
        int c = idx4 >> 5, y4 = (idx4 & 31) * 4;
        int cg = cc * 32 + c;
        const float4 r = *(const float4*)(fmap + (((size_t)(b * 128 + cg)) * 128 + x) * 128 + y4);
        float mu = muS[cg], rs = rsS[cg];
        float4 g = *(const float4*)(g0S + y4);
        float4 be = *(const float4*)(b0S + y4);
        float4 o;
        o.x = (r.x - mu) * rs * g.x + be.x;
        o.y = (r.y - mu) * rs * g.y + be.y;
        o.z = (r.z - mu) * rs * g.z + be.z;
        o.w = (r.w - mu) * rs * g.w + be.w;
        *(float4*)(fmS + c * 128 + y4) = o;
      }
      #pragma unroll
      for (int it = 0; it < 2; ++it) {          // stage weight chunk (k||v of 2 heads)
        int idx4 = it * 512 + t;
        int c = idx4 >> 5, rr = (idx4 & 31) * 4;
        int h = blk * 2 + (rr >> 6);
        int rl = rr & 63;
        int o = (rl < 32) ? (256 + h * 32 + rl) : (512 + h * 32 + (rl - 32));
        *(float4*)(wS + c * 128 + rr) = *(const float4*)(ws + OFF_WT + (size_t)(cc * 32 + c) * 768 + o);
      }
      __syncthreads();
      #pragma unroll 8
      for (int c = 0; c < 32; ++c) {
        const float4 w0 = *(const float4*)(wS + c * 128 + og * 8);
        const float4 w1 = *(const float4*)(wS + c * 128 + og * 8 + 4);
        const float4 f  = *(const float4*)(fmS + c * 128 + yg * 4);
        const float wv[8] = {w0.x, w0.y, w0.z, w0.w, w1.x, w1.y, w1.z, w1.w};
        const float fv[4] = {f.x, f.y, f.z, f.w};
        #pragma unroll
        for (int i = 0; i < 8; ++i)
          #pragma unroll
          for (int j = 0; j < 4; ++j)
            acc[i][j] = fmaf(wv[i], fv[j], acc[i][j]);
      }
    }

    for (int hh = 0; hh < 2; ++hh) {            // head = blk*2 + hh
      float u[16], se[4];
      #pragma unroll
      for (int i = 0; i < 16; ++i) u[i] = 0.0f;
      se[0] = se[1] = se[2] = se[3] = 0.0f;

      for (int hf = 0; hf < 2; ++hf) {          // y halves of 64
        if (((og >> 3) == hh) && ((yg >> 4) == hf)) {  // wave-uniform predicate
          int ogl = og & 7;
          int yl = (yg & 15) * 4;
          if (ogl < 4) {                        // k rows: exp, d = ogl*8+jj
            #pragma unroll
            for (int yy = 0; yy < 4; ++yy) {
              float4 p0, p1;
              p0.x = __expf(acc[0][yy]); p0.y = __expf(acc[1][yy]);
              p0.z = __expf(acc[2][yy]); p0.w = __expf(acc[3][yy]);
              p1.x = __expf(acc[4][yy]); p1.y = __expf(acc[5][yy]);
              p1.z = __expf(acc[6][yy]); p1.w = __expf(acc[7][yy]);
              *(float4*)(pb + (yl + yy) * 36 + ogl * 8) = p0;
              *(float4*)(pb + (yl + yy) * 36 + ogl * 8 + 4) = p1;
            }
          } else {                              // v rows raw + sumsq partials
            int ov = ogl - 4;
            float4 sv;
            float* svp = &sv.x;
            #pragma unroll
            for (int yy = 0; yy < 4; ++yy) {
              float4 v0, v1;
              v0.x = acc[0][yy]; v0.y = acc[1][yy]; v0.z = acc[2][yy]; v0.w = acc[3][yy];
              v1.x = acc[4][yy]; v1.y = acc[5][yy]; v1.z = acc[6][yy]; v1.w = acc[7][yy];
              *(float4*)(vb + (yl + yy) * 36 + ov * 8) = v0;
              *(float4*)(vb + (yl + yy) * 36 + ov * 8 + 4) = v1;
              float s = 0.0f;
              #pragma unroll
              for (int j = 0; j < 8; ++j) s = fmaf(acc[j][yy], acc[j][yy], s);
              svp[yy] = s;
            }
            *(float4*)(vss + ov * 64 + yl) = sv;
          }
        }
        __syncthreads();
        if (t < 64) {                           // rn per y (v l2-norm reciprocal)
          float s2 = vss[t] + vss[64 + t] + vss[128 + t] + vss[192 + t];
          rnS[t] = 1.0f / fmaxf(sqrtf(s2), 1e-12f);
        }
        __syncthreads();
        #pragma unroll 2
        for (int yy = 0; yy < 8; ++yy) {        // U tile: (4d x 4e) per lane, wave=yseg
          int y = wave * 8 + yy;
          const float4 p = *(const float4*)(pb + y * 36 + dt * 4);
          float4 v = *(const float4*)(vb + y * 36 + et * 4);
          float rn = rnS[y];
          v.x *= rn; v.y *= rn; v.z *= rn; v.w *= rn;
          se[0] += p.x; se[1] += p.y; se[2] += p.z; se[3] += p.w;
          u[0]  = fmaf(p.x, v.x, u[0]);  u[1]  = fmaf(p.x, v.y, u[1]);
          u[2]  = fmaf(p.x, v.z, u[2]);  u[3]  = fmaf(p.x, v.w, u[3]);
          u[4]  = fmaf(p.y, v.x, u[4]);  u[5]  = fmaf(p.y, v.y, u[5]);
          u[6]  = fmaf(p.y, v.z, u[6]);  u[7]  = fmaf(p.y, v.w, u[7]);
          u[8]  = fmaf(p.z, v.x, u[8]);  u[9]  = fmaf(p.z, v.y, u[9]);
          u[10] = fmaf(p.z, v.z, u[10]); u[11] = fmaf(p.z, v.w, u[11]);
          u[12] = fmaf(p.w, v.x, u[12]); u[13] = fmaf(p.w, v.y, u[13]);
          u[14] = fmaf(p.w, v.z, u[14]); u[15] = fmaf(p.w, v.w, u[15]);
        }
        __syncthreads();                        // before pbuf/vbuf reuse
      }
      // write partial tiles into red (aliases fm+w region, dead until next cc stage)
      *(float4*)(sm + t * 16 + 0)  = make_float4(u[0], u[1], u[2], u[3]);
      *(float4*)(sm + t * 16 + 4)  = make_float4(u[4], u[5], u[6], u[7]);
      *(float4*)(sm + t * 16 + 8)  = make_float4(u[8], u[9], u[10], u[11]);
      *(float4*)(sm + t * 16 + 12) = make_float4(u[12], u[13], u[14], u[15]);
      if (et == 0)
        *(float4*)(ser + (wave * 8 + dt) * 4) = make_float4(se[0], se[1], se[2], se[3]);
      __syncthreads();
      {
        const int tile = t >> 3;
        const int i0 = (t & 7) * 2;
        float s0 = 0.0f, s1 = 0.0f;
        #pragma unroll
        for (int w = 0; w < 8; ++w) {
          s0 += sm[(w * 64 + tile) * 16 + i0];
          s1 += sm[(w * 64 + tile) * 16 + i0 + 1];
        }
        const int d = (tile >> 3) * 4 + (i0 >> 2);
        const int e = (tile & 7) * 4 + (i0 & 3);
        float* ca = ws + OFF_CTXA + ((size_t)(b * 8 + blk * 2 + hh) * 16 + xg) * 1056;
        atomicAdd(ca + d * 32 + e, s0);
        atomicAdd(ca + d * 32 + e + 1, s1);
        if (t < 32) {
          float ss = 0.0f;
          #pragma unroll
          for (int w = 0; w < 8; ++w) ss += ser[(w * 8 + (t >> 2)) * 4 + (t & 3)];
          atomicAdd(ca + 1024 + t, ss);
        }
      }
    }
  }
}

// ---------------- reduce x-group partials, fold scales ----------------
__global__ void ctx_reduce_kernel(float* __restrict__ ws) {
  __shared__ float sume[32];
  const int bh = blockIdx.x, t = threadIdx.x;
  const float* ca = ws + OFF_CTXA + (size_t)bh * 16 * 1056;
  if (t < 32) {
    double a = 0.0;
    #pragma unroll
    for (int xg = 0; xg < 16; ++xg) a += ca[xg * 1056 + 1024 + t];
    sume[t] = (float)a;
  }
  __syncthreads();
  const double sb = (1.0 / 16384.0) * 0.17677669529663688;  // inv^2 * dh^-0.5
  #pragma unroll
  for (int i = 0; i < 4; ++i) {
    int de = t + 256 * i;
    double a = 0.0;
    #pragma unroll
    for (int xg = 0; xg < 16; ++xg) a += ca[xg * 1056 + de];
    ws[OFF_CTXS + (size_t)bh * 1024 + de] = (float)(a * sb / (double)sume[de >> 5]);
  }
}

// ---------------- final: Q matmul -> softmax -> q@ctx -> gelu -> out-conv -> LN1 ----------------
// LDS floats: fm[32][128]@0, wq/woS[32][128]@4096 (red_s@0/red_q@4096 at LN1),
// qh[32][132]@8192, ctxS[1024]@12416, muS@13440,rsS,g0S,b0S, lnm@13952, lnr@14080 -> 14208 = 56.8 KB
__launch_bounds__(512, 4)
__global__ void final_kernel(const float* __restrict__ fmap,
                             const float* __restrict__ g0,
                             const float* __restrict__ b0,
                             const float* __restrict__ g1,
                             const float* __restrict__ b1,
                             const float* __restrict__ ws,
                             float* __restrict__ out) {
  __shared__ float sm[14208];
  const int x = blockIdx.x, b = blockIdx.y, t = threadIdx.x;
  const int wave = t >> 6, lane = t & 63;
  const int og = (wave >> 1) * 4 + (lane >> 4);  // 0..15
  const int yg = (wave & 1) * 16 + (lane & 15);  // 0..31
  const int yq = t & 127, eg = t >> 7;           // qctx mapping
  float* fmS = sm;
  float* wS  = sm + 4096;
  float* qh  = sm + 8192;     // [32][132]
  float* ctxS = sm + 12416;
  float* muS = sm + 13440;
  float* rsS = sm + 13568;
  float* g0S = sm + 13696;
  float* b0S = sm + 13824;
  float* lnm = sm + 13952;
  float* lnr = sm + 14080;

  if (t < 128) {
    muS[t] = ws[OFF_MU + (unsigned)((b * 128 + t) * 128 + x)];
    rsS[t] = ws[OFF_RSTD + (unsigned)((b * 128 + t) * 128 + x)];
  } else if (t < 256) g0S[t - 128] = g0[t - 128];
  else if (t < 384) b0S[t - 256] = b0[t - 256];

  float o2[8][4];
  #pragma unroll
  for (int i = 0; i < 8; ++i)
    #pragma unroll
    for (int j = 0; j < 4; ++j) o2[i][j] = 0.0f;

  for (int qblk = 0; qblk < 2; ++qblk) {
    float qa[8][4];
    #pragma unroll
    for (int i = 0; i < 8; ++i)
      #pragma unroll
      for (int j = 0; j < 4; ++j) qa[i][j] = 0.0f;

    for (int cc = 0; cc < 4; ++cc) {
      __syncthreads();
      #pragma unroll
      for (int it = 0; it < 2; ++it) {
        int idx4 = it * 512 + t;
        int c = idx4 >> 5, y4 = (idx4 & 31) * 4;
        int cg = cc * 32 + c;
        const float4 r = *(const float4*)(fmap + (((size_t)(b * 128 + cg)) * 128 + x) * 128 + y4);
        float mu = muS[cg], rs = rsS[cg];
        float4 g = *(const float4*)(g0S + y4);
        float4 be = *(const float4*)(b0S + y4);
        float4 o;
        o.x = (r.x - mu) * rs * g.x + be.x;
        o.y = (r.y - mu) * rs * g.y + be.y;
        o.z = (r.z - mu) * rs * g.z + be.z;
        o.w = (r.w - mu) * rs * g.w + be.w;
        *(float4*)(fmS + c * 128 + y4) = o;
      }
      #pragma unroll
      for (int it = 0; it < 2; ++it) {
        int idx4 = it * 512 + t;
        int c = idx4 >> 5, rr = (idx4 & 31) * 4;
        int o = qblk * 128 + rr;
        *(float4*)(wS + c * 128 + rr) = *(const float4*)(ws + OFF_WT + (size_t)(cc * 32 + c) * 768 + o);
      }
      __syncthreads();
      #pragma unroll 8
      for (int c = 0; c < 32; ++c) {
        const float4 w0 = *(const float4*)(wS + c * 128 + og * 8);
        const float4 w1 = *(const float4*)(wS + c * 128 + og * 8 + 4);
        const float4 f  = *(const float4*)(fmS + c * 128 + yg * 4);
        const float wv[8] = {w0.x, w0.y, w0.z, w0.w, w1.x, w1.y, w1.z, w1.w};
        const float fv[4] = {f.x, f.y, f.z, f.w};
        #pragma unroll
        for (int i = 0; i < 8; ++i)
          #pragma unroll
          for (int j = 0; j < 4; ++j)
            qa[i][j] = fmaf(wv[i], fv[j], qa[i][j]);
      }
    }

    for (int hh = 0; hh < 4; ++hh) {            // head = qblk*4 + hh
      __syncthreads();                          // S1: qh/wS free of prior readers
      if ((og >> 2) == hh) {                    // transpose this head's q rows
        int dl = (og & 3) * 8;
        #pragma unroll
        for (int jj = 0; jj < 8; ++jj)
          *(float4*)(qh + (dl + jj) * 132 + yg * 4) =
              make_float4(qa[jj][0], qa[jj][1], qa[jj][2], qa[jj][3]);
      }
      if (t < 256)
        *(float4*)(ctxS + t * 4) =
            *(const float4*)(ws + OFF_CTXS + (size_t)(b * 8 + qblk * 4 + hh) * 1024 + t * 4);
      __syncthreads();                          // S2
      // softmax over d (no max-shift needed: |q| small) + q@ctx; e split 4 ways
      float ge[8];
      #pragma unroll
      for (int i = 0; i < 8; ++i) ge[i] = 0.0f;
      float ssum = 0.0f;
      #pragma unroll 4
      for (int dd = 0; dd < 32; ++dd) {
        float p = __expf(qh[dd * 132 + yq]);
        ssum += p;
        const float4 c0 = *(const float4*)(ctxS + dd * 32 + eg * 8);
        const float4 c1 = *(const float4*)(ctxS + dd * 32 + eg * 8 + 4);
        ge[0] = fmaf(p, c0.x, ge[0]); ge[1] = fmaf(p, c0.y, ge[1]);
        ge[2] = fmaf(p, c0.z, ge[2]); ge[3] = fmaf(p, c0.w, ge[3]);
        ge[4] = fmaf(p, c1.x, ge[4]); ge[5] = fmaf(p, c1.y, ge[5]);
        ge[6] = fmaf(p, c1.z, ge[6]); ge[7] = fmaf(p, c1.w, ge[7]);
      }
      const float rinv = 1.0f / ssum;
      // stage woS chunk for this head (wS free: q-matmul done, prev out-conv pre-S1)
      #pragma unroll
      for (int it = 0; it < 2; ++it) {
        int idx4 = it * 512 + t;
        int c = idx4 >> 5, o4 = (idx4 & 31) * 4;
        *(float4*)(wS + c * 128 + o4) =
            *(const float4*)(ws + OFF_WOT + (size_t)(qblk * 128 + hh * 32 + c) * 128 + o4);
      }
      __syncthreads();                          // S3: all qh reads done
      #pragma unroll
      for (int i = 0; i < 8; ++i) {             // gelu (erf), write in place
        float v = ge[i] * rinv;
        qh[(eg * 8 + i) * 132 + yq] = 0.5f * v * (1.0f + erff(v * 0.70710678118654752f));
      }
      __syncthreads();                          // S4: gel + woS visible
      #pragma unroll 4
      for (int cp = 0; cp < 32; ++cp) {         // out-conv partial accumulate
        const float4 w0 = *(const float4*)(wS + cp * 128 + og * 8);
        const float4 w1 = *(const float4*)(wS + cp * 128 + og * 8 + 4);
        const float4 gl = *(const float4*)(qh + cp * 132 + yg * 4);
        const float wv[8] = {w0.x, w0.y, w0.z, w0.w, w1.x, w1.y, w1.z, w1.w};
        const float gv[4] = {gl.x, gl.y, gl.z, gl.w};
        #pragma unroll
        for (int i = 0; i < 8; ++i)
          #pragma unroll
          for (int j = 0; j < 4; ++j)
            o2[i][j] = fmaf(wv[i], gv[j], o2[i][j]);
      }
    }
  }

  // ---- LN1 over y per o-row ----
  __syncthreads();
  #pragma unroll
  for (int oo = 0; oo < 8; ++oo) {
    float s = 0.0f, q = 0.0f;
    #pragma unroll
    for (int j = 0; j < 4; ++j) { float v = o2[oo][j]; s += v; q = fmaf(v, v, q); }
    sm[(og * 8 + oo) * 32 + yg] = s;            // red_s @ fm region
    sm[4096 + (og * 8 + oo) * 32 + yg] = q;     // red_q @ w region
  }
  __syncthreads();
  if (t < 128) {
    double s = 0.0, q = 0.0;
    #pragma unroll
    for (int i = 0; i < 32; ++i) { s += sm[t * 32 + i]; q += sm[4096 + t * 32 + i]; }
    double mu = s * (1.0 / 128.0);
    double var = q * (1.0 / 128.0) - mu * mu;
    lnm[t] = (float)mu;
    lnr[t] = (float)(1.0 / sqrt(var + 1e-5));
  }
  __syncthreads();
  const float4 g1v = *(const float4*)(g1 + yg * 4);
  const float4 b1v = *(const float4*)(b1 + yg * 4);
  #pragma unroll
  for (int oo = 0; oo < 8; ++oo) {
    int o = og * 8 + oo;
    float mu = lnm[o], rs = lnr[o];
    float4 r;
    r.x = (o2[oo][0] - mu) * rs * g1v.x + b1v.x;
    r.y = (o2[oo][1] - mu) * rs * g1v.y + b1v.y;
    r.z = (o2[oo][2] - mu) * rs * g1v.z + b1v.z;
    r.w = (o2[oo][3] - mu) * rs * g1v.w + b1v.w;
    *(float4*)(out + (((size_t)(b * 128 + o)) * 128 + x) * 128 + yg * 4) = r;
  }
}

extern "C" void kernel_launch(void* const* d_in, const int* in_sizes, int n_in,
                              void* d_out, int out_size, void* d_ws, size_t ws_size,
                              hipStream_t stream) {
  const float* fmap = (const float*)d_in[0];
  const float* g0   = (const float*)d_in[1];
  const float* b0   = (const float*)d_in[2];
  const float* wqkv = (const float*)d_in[3];
  const float* wout = (const float*)d_in[4];
  const float* g1   = (const float*)d_in[5];
  const float* b1   = (const float*)d_in[6];
  float* ws  = (float*)d_ws;
  float* out = (float*)d_out;

  hipMemsetAsync((char*)d_ws + (size_t)OFF_CTXA * 4, 0, (size_t)2162688 * 4, stream);
  prep_kernel<<<512, 256, 0, stream>>>(wqkv, wout, ws);
  ln0_stats_kernel<<<65536, 256, 0, stream>>>(fmap, ws);
  kv_ctx_kernel<<<dim3(128, 16), 512, 0, stream>>>(fmap, g0, b0, ws);
  ctx_reduce_kernel<<<128, 256, 0, stream>>>(ws);
  final_kernel<<<dim3(128, 16), 512, 0, stream>>>(fmap, g0, b0, g1, b1, ws, out);
}